// Round 6
// baseline (278.458 us; speedup 1.0000x reference)
//
#include <hip/hip_runtime.h>
#include <hip/hip_bf16.h>
#include <math.h>

typedef float  f32x4  __attribute__((ext_vector_type(4)));
typedef float  f32x16 __attribute__((ext_vector_type(16)));
typedef short  s16x8  __attribute__((ext_vector_type(8)));
typedef __bf16 bf16x8 __attribute__((ext_vector_type(8)));
typedef unsigned int u32;
typedef unsigned int u32x4 __attribute__((ext_vector_type(4)));
typedef unsigned short u16;
typedef unsigned long long u64;

#define DEVI static __device__ __forceinline__

#if defined(__has_builtin) && __has_builtin(__builtin_amdgcn_exp2f)
#define EXP2(x) __builtin_amdgcn_exp2f(x)
#else
#define EXP2(x) exp2f(x)
#endif

// one-instruction packed f32->bf16 RNE pair (v_cvt_pk_bf16_f32)
DEVI u32 cvtpk(float lo, float hi) {
  u32 r;
  asm("v_cvt_pk_bf16_f32 %0, %1, %2" : "=v"(r) : "v"(lo), "v"(hi));
  return r;
}

DEVI f32x4 mfma_bf16(s16x8 a, s16x8 b, f32x4 c) {
  return __builtin_amdgcn_mfma_f32_16x16x32_bf16(
      __builtin_bit_cast(bf16x8, a), __builtin_bit_cast(bf16x8, b), c, 0, 0, 0);
}

DEVI f32x16 mfma32(s16x8 a, s16x8 b, f32x16 c) {
  return __builtin_amdgcn_mfma_f32_32x32x16_bf16(
      __builtin_bit_cast(bf16x8, a), __builtin_bit_cast(bf16x8, b), c, 0, 0, 0);
}

DEVI void gload_lds16(const void* g, void* l) {
  __builtin_amdgcn_global_load_lds(
      (const __attribute__((address_space(1))) void*)g,
      (__attribute__((address_space(3))) void*)l, 16, 0, 0);
}

// ---------------------------------------------------------------------------
// Kernel 1: QKV projections + fused mask bit-pack.
//  blockIdx.x <  128: GEMM tiles. z=0: Q (scaled 1/8*log2e)  z=1: K
//                     z=2: V transposed -> VT[b*512+h*64+d][s]
//  blockIdx.x >= 128: pack KEEP bits: int32 mask -> u64[8][32][2048]
//                     (bit l of word (b,kt,q) == 1 iff mask[b][q][kt*64+l]==0)
// grid (192, 4, 3), block 256.
// ---------------------------------------------------------------------------
__global__ __launch_bounds__(256, 2)
void qkv_proj(const float* __restrict__ xq, const float* __restrict__ xkv,
              const float* __restrict__ wq, const float* __restrict__ bq,
              const float* __restrict__ wk, const float* __restrict__ bk,
              const float* __restrict__ wv, const float* __restrict__ bv,
              const int* __restrict__ maskp, u64* __restrict__ mp,
              u16* __restrict__ Qo, u16* __restrict__ Ko, u16* __restrict__ VTo)
{
  const int t = threadIdx.x, lane = t & 63, w = t >> 6;

  if (blockIdx.x >= 128) {              // ---- mask bit-pack path ----
    const u32 mb = (blockIdx.z * 4 + blockIdx.y) * 64 + (blockIdx.x - 128);
    const u32 wave = mb * 4 + w;
    u32 wid = wave * 171u;
    u32 wend = wid + 171u; if (wend > 524288u) wend = 524288u;
    if (wid >= wend) return;
    // src index for word W: b=W>>16, kt=(W>>11)&31, q=W&2047
    #define MSRC(W) (((size_t)((((W) >> 16) << 11) + ((W) & 2047u))) * 2048 \
                     + (((W) >> 11) & 31u) * 64 + lane)
    int cur = maskp[MSRC(wid)];
    for (u32 W = wid; W < wend; ++W) {
      int nxt = (W + 1 < wend) ? maskp[MSRC(W + 1)] : 0;
      u64 bits = __ballot(cur == 0);
      if (lane == 0) mp[W] = bits;
      cur = nxt;
    }
    #undef MSRC
    return;
  }

  __shared__ __align__(16) char smem[128 * 272]; // A[0,8K) B[8K,16K); V-transpose
  char* lds_a = smem;
  char* lds_b = smem + 8192;

  const int z = blockIdx.z;
  const float* X  = (z == 0) ? xq : xkv;
  const float* W  = (z == 0) ? wq : (z == 1 ? wk : wv);
  const float* Bv = (z == 0) ? bq : (z == 1 ? bk : bv);

  const int m0 = blockIdx.x * 128, n0 = blockIdx.y * 128;
  const int wr = w >> 1, wc = w & 1, g = lane >> 4, q15 = lane & 15;
  const int srow = t >> 1, shalf = t & 1;

  f32x4 acc[4][4];
  #pragma unroll
  for (int i = 0; i < 4; ++i)
    #pragma unroll
    for (int j = 0; j < 4; ++j) acc[i][j] = (f32x4){0.f, 0.f, 0.f, 0.f};

  const float* gA = X + (size_t)(m0 + srow) * 512 + shalf * 16;
  const float* gB = W + (size_t)(n0 + srow) * 512 + shalf * 16;
  const int wbyte = srow * 64;
  const int sw = (srow & 3) << 4;

  #pragma unroll 1
  for (int kt = 0; kt < 16; ++kt) {
    float4 fa[4], fb[4];
    #pragma unroll
    for (int j = 0; j < 4; ++j) {
      fa[j] = *(const float4*)(gA + kt * 32 + j * 4);
      fb[j] = *(const float4*)(gB + kt * 32 + j * 4);
    }
    __syncthreads();                    // prev compute done before overwrite
    const float* pfa = (const float*)fa;
    const float* pfb = (const float*)fb;
    #pragma unroll
    for (int half = 0; half < 2; ++half) {
      u32x4 wa, wb;
      #pragma unroll
      for (int e2 = 0; e2 < 4; ++e2) {
        wa[e2] = cvtpk(pfa[half * 8 + 2 * e2], pfa[half * 8 + 2 * e2 + 1]);
        wb[e2] = cvtpk(pfb[half * 8 + 2 * e2], pfb[half * 8 + 2 * e2 + 1]);
      }
      *(u32x4*)(lds_a + wbyte + ((shalf * 32 + half * 16) ^ sw)) = wa;
      *(u32x4*)(lds_b + wbyte + ((shalf * 32 + half * 16) ^ sw)) = wb;
    }
    __syncthreads();
    s16x8 afr[4], bfr[4];
    #pragma unroll
    for (int mi = 0; mi < 4; ++mi) {
      int row = wr * 64 + mi * 16 + q15;
      afr[mi] = *(const s16x8*)(lds_a + row * 64 + ((g * 16) ^ ((row & 3) << 4)));
    }
    #pragma unroll
    for (int ni = 0; ni < 4; ++ni) {
      int row = wc * 64 + ni * 16 + q15;
      bfr[ni] = *(const s16x8*)(lds_b + row * 64 + ((g * 16) ^ ((row & 3) << 4)));
    }
    #pragma unroll
    for (int mi = 0; mi < 4; ++mi)
      #pragma unroll
      for (int ni = 0; ni < 4; ++ni)
        acc[mi][ni] = mfma_bf16(afr[mi], bfr[ni], acc[mi][ni]);
  }

  float bias[4];
  #pragma unroll
  for (int ni = 0; ni < 4; ++ni) bias[ni] = Bv[n0 + wc * 64 + ni * 16 + q15];

  if (z < 2) {
    u16* Out = z ? Ko : Qo;
    // Q: fold 1/sqrt(64) * log2(e) so attention works in exp2 domain
    const float scale = z ? 1.0f : 0.18033688011112042f;
    #pragma unroll
    for (int mi = 0; mi < 4; ++mi)
      #pragma unroll
      for (int ni = 0; ni < 4; ++ni)
        #pragma unroll
        for (int r = 0; r < 4; r += 2) {
          int m = m0 + wr * 64 + mi * 16 + g * 4 + r;
          int n = n0 + wc * 64 + ni * 16 + q15;
          u32 pk = cvtpk((acc[mi][ni][r] + bias[ni]) * scale,
                         (acc[mi][ni][r + 1] + bias[ni]) * scale);
          Out[(size_t)m * 512 + n]       = (u16)pk;
          Out[(size_t)(m + 1) * 512 + n] = (u16)(pk >> 16);
        }
  } else {
    __syncthreads();                    // all frag reads done; reuse smem
    #pragma unroll
    for (int mi = 0; mi < 4; ++mi)
      #pragma unroll
      for (int ni = 0; ni < 4; ++ni)
        #pragma unroll
        for (int r = 0; r < 4; r += 2) {
          int ml = wr * 64 + mi * 16 + g * 4 + r;
          int nl = wc * 64 + ni * 16 + q15;
          *(u32*)(smem + nl * 272 + ml * 2) =
              cvtpk(acc[mi][ni][r] + bias[ni], acc[mi][ni][r + 1] + bias[ni]);
        }
    __syncthreads();
    const int b  = m0 >> 11;
    const int s0 = m0 & 2047;
    #pragma unroll
    for (int nn = 0; nn < 2; ++nn) {
      int n  = nn * 64 + (t >> 2);
      int q4 = t & 3;
      u16* dst = VTo + (size_t)(b * 512 + n0 + n) * 2048 + s0 + q4 * 32;
      #pragma unroll
      for (int jj = 0; jj < 4; ++jj)
        *(s16x8*)(dst + jj * 8) = *(const s16x8*)(smem + n * 272 + q4 * 64 + jj * 16);
    }
  }
}

// ---------------------------------------------------------------------------
// Kernel 2: fused flash attention, 32x32 MFMA form, no-max exp2 softmax.
// Row denominators via ones-column MFMA (o2): P (masked, bf16-packed) feeds
// both PV and the sum -> no VALU lsum, no epilogue shuffles.
// grid.x = h + 8*b + 64*qt; block 256 = 4 waves x 32 q-rows.
// ---------------------------------------------------------------------------
__global__ __launch_bounds__(256, 3)
void attn_fwd(const u16* __restrict__ Q, const u16* __restrict__ K,
              const u16* __restrict__ VT, const u64* __restrict__ MP,
              float* __restrict__ out)
{
  __shared__ __align__(16) char lds_k[2][8192];  // [kv 64][d 64] bf16, swizzled
  __shared__ __align__(16) char lds_v[2][8192];  // [d 64][kv 64] bf16, swizzled

  const int bid = blockIdx.x;
  const int h = bid & 7, b = (bid >> 3) & 7, qt = bid >> 6;
  const int t = threadIdx.x, lane = t & 63, w = t >> 6;
  const int l31 = lane & 31, hi = lane >> 5;
  const int qbase = qt * 128 + w * 32;
  const int swz = (l31 & 7) << 4;

  // Q B-frags (pre-scaled by 0.125*log2e): col=q=l31, k(d) = j*16 + 8*hi + e
  s16x8 qf[4];
  #pragma unroll
  for (int j = 0; j < 4; ++j)
    qf[j] = *(const s16x8*)(Q + (size_t)(b * 2048 + qbase + l31) * 512
                              + h * 64 + j * 16 + hi * 8);
  asm volatile("" ::: "memory");        // pin qf loads before STAGE(0)

  f32x16 o0 = {0.f,0.f,0.f,0.f,0.f,0.f,0.f,0.f,0.f,0.f,0.f,0.f,0.f,0.f,0.f,0.f};
  f32x16 o1 = o0, o2 = o0;
  const f32x16 ZZ = o0;
  const s16x8 onesf = {0x3F80,0x3F80,0x3F80,0x3F80,0x3F80,0x3F80,0x3F80,0x3F80};

  const int srow8 = lane >> 3, slot = lane & 7;
  const int rl0 = w * 16 + srow8, rl1 = rl0 + 8;

  // loop-carried staging pointers (advance by consts; no per-iter recompute)
  const u16* kP0 = K + (size_t)(b * 2048 + rl0) * 512 + h * 64 + (slot ^ (rl0 & 7)) * 8;
  const u16* kP1 = K + (size_t)(b * 2048 + rl1) * 512 + h * 64 + (slot ^ (rl1 & 7)) * 8;
  const u16* vP0 = VT + (size_t)(b * 512 + h * 64 + rl0) * 2048 + (slot ^ (rl0 & 7)) * 8;
  const u16* vP1 = VT + (size_t)(b * 512 + h * 64 + rl1) * 2048 + (slot ^ (rl1 & 7)) * 8;
  const u64* mpP = MP + (size_t)b * 32 * 2048 + qbase + l31;

  // prologue: stage tile 0 into buf 0, prefetch mask word 0
  gload_lds16(kP0, &lds_k[0][w * 2048]);
  gload_lds16(vP0, &lds_v[0][w * 2048]);
  gload_lds16(kP1, &lds_k[0][w * 2048 + 1024]);
  gload_lds16(vP1, &lds_v[0][w * 2048 + 1024]);
  asm volatile("" ::: "memory");        // stage(0) issued before mask prefetch
  u64 pm = *mpP;

  #pragma unroll 1
  for (int kt = 0; kt < 32; ++kt) {
    const int cur = kt & 1;
    const u64 kw = pm;
    if (kt + 1 < 32) {
      kP0 += 32768; kP1 += 32768; vP0 += 64; vP1 += 64; mpP += 2048;
      gload_lds16(kP0, &lds_k[cur ^ 1][w * 2048]);
      gload_lds16(vP0, &lds_v[cur ^ 1][w * 2048]);
      gload_lds16(kP1, &lds_k[cur ^ 1][w * 2048 + 1024]);
      gload_lds16(vP1, &lds_v[cur ^ 1][w * 2048 + 1024]);
      asm volatile("" ::: "memory");
      pm = *mpP;
      // newer than {stage(kt), mask(kt)}: stage(kt+1)=4 + mask(kt+1)=1 = 5
      asm volatile("s_waitcnt vmcnt(5)" ::: "memory");
    } else {
      asm volatile("s_waitcnt vmcnt(0)" ::: "memory");
    }
    asm volatile("s_barrier" ::: "memory");

    // ---- S^T = K * Q^T over d=64 (4 mfma per kv-32 tile) ----
    f32x16 p0, p1;
    {
      s16x8 a0 = *(const s16x8*)(&lds_k[cur][ l31       * 128 + ((0 * 32 + hi * 16) ^ swz)]);
      s16x8 a1 = *(const s16x8*)(&lds_k[cur][(l31 + 32) * 128 + ((0 * 32 + hi * 16) ^ swz)]);
      p0 = mfma32(a0, qf[0], ZZ);
      p1 = mfma32(a1, qf[0], ZZ);
    }
    #pragma unroll
    for (int j = 1; j < 4; ++j) {
      s16x8 a0 = *(const s16x8*)(&lds_k[cur][ l31       * 128 + ((j * 32 + hi * 16) ^ swz)]);
      s16x8 a1 = *(const s16x8*)(&lds_k[cur][(l31 + 32) * 128 + ((j * 32 + hi * 16) ^ swz)]);
      p0 = mfma32(a0, qf[j], p0);
      p1 = mfma32(a1, qf[j], p1);
    }

    // ---- masked exp2 -> packed bf16 words (raw v_exp_f32, v_cvt_pk) ----
    // own kv of word (t2,q): 32*t2 + 8*(q>>1) + 2*(q&1) + 4*hi (+0/+1)
    u64 kws = kw >> (hi * 4);
    u32 mm0 = (u32)kws, mm1 = (u32)(kws >> 32);
    u32 wds[16];
    #pragma unroll
    for (int t2 = 0; t2 < 2; ++t2) {
      const u32 mmw = t2 ? mm1 : mm0;
      #pragma unroll
      for (int q = 0; q < 8; ++q) {
        const int bp = 8 * (q >> 1) + 2 * (q & 1);
        float s0v = t2 ? p1[2 * q] : p0[2 * q];
        float s1v = t2 ? p1[2 * q + 1] : p0[2 * q + 1];
        float e0 = EXP2(s0v), e1 = EXP2(s1v);
        u32 k0 = (u32)((int)(mmw << (31 - bp)) >> 31);        // sext bit bp
        u32 k1 = (u32)((int)(mmw << (30 - bp)) >> 31);        // sext bit bp+1
        e0 = __builtin_bit_cast(float, __builtin_bit_cast(u32, e0) & k0);
        e1 = __builtin_bit_cast(float, __builtin_bit_cast(u32, e1) & k1);
        wds[t2 * 8 + q] = cvtpk(e0, e1);
      }
    }

    // ---- PV + ones-column row sums: per j exchange 2 word-pairs (lane^32),
    //      then 3 mfma (o0, o1, o2-sum) ----
    #pragma unroll
    for (int j = 0; j < 4; ++j) {
      const int ia = 2 * j, ib = 2 * j + 1;
      u32 wa0 = wds[(ia >> 2) * 8 + 2 * (ia & 3)];
      u32 wa1 = wds[(ia >> 2) * 8 + 2 * (ia & 3) + 1];
      u32 wb0 = wds[(ib >> 2) * 8 + 2 * (ib & 3)];
      u32 wb1 = wds[(ib >> 2) * 8 + 2 * (ib & 3) + 1];
      asm("v_permlane32_swap_b32 %0, %1" : "+v"(wa0), "+v"(wb0));
      asm("v_permlane32_swap_b32 %0, %1" : "+v"(wa1), "+v"(wb1));
      u32x4 aw = {wa0, wa1, wb0, wb1};
      s16x8 af = __builtin_bit_cast(s16x8, aw);
      s16x8 v0 = *(const s16x8*)(&lds_v[cur][ l31       * 128 + ((j * 32 + hi * 16) ^ swz)]);
      s16x8 v1 = *(const s16x8*)(&lds_v[cur][(l31 + 32) * 128 + ((j * 32 + hi * 16) ^ swz)]);
      o0 = mfma32(af, v0, o0);
      o1 = mfma32(af, v1, o1);
      o2 = mfma32(af, onesf, o2);
    }

    asm volatile("s_waitcnt lgkmcnt(0)" ::: "memory");
    __builtin_amdgcn_sched_barrier(0);
    asm volatile("s_barrier" ::: "memory");   // reads done before next overwrite
  }

  // ---- epilogue: o2[reg] IS the row denominator for o0/o1[reg] ----
  #pragma unroll
  for (int reg = 0; reg < 16; ++reg) {
    const int ql = (reg & 3) + 8 * (reg >> 2) + 4 * hi;
    const float linv = 1.0f / o2[reg];
    float* po = out + (size_t)(b * 2048 + qbase + ql) * 512 + h * 64 + l31;
    po[0]  = o0[reg] * linv;
    po[32] = o1[reg] * linv;
  }
}

extern "C" void kernel_launch(void* const* d_in, const int* in_sizes, int n_in,
                              void* d_out, int out_size, void* d_ws, size_t ws_size,
                              hipStream_t stream) {
  const float* xq  = (const float*)d_in[0];
  const float* xkv = (const float*)d_in[1];
  const int*   msk = (const int*)d_in[2];
  const float* wq  = (const float*)d_in[3];
  const float* bq  = (const float*)d_in[4];
  const float* wk  = (const float*)d_in[5];
  const float* bk  = (const float*)d_in[6];
  const float* wv  = (const float*)d_in[7];
  const float* bv  = (const float*)d_in[8];

  u16* Qw = (u16*)d_ws;                          // [16384][512] bf16 (x 0.1803)
  u16* Kw = Qw + (size_t)16384 * 512;            // [16384][512] bf16
  u16* VT = Kw + (size_t)16384 * 512;            // [4096][2048] bf16 (V^T)
  u64* MP = (u64*)(VT + (size_t)4096 * 2048);    // [8][32][2048] packed keep bits

  qkv_proj<<<dim3(192, 4, 3), 256, 0, stream>>>(xq, xkv, wq, bq, wk, bk, wv, bv,
                                                msk, MP, Qw, Kw, VT);
  attn_fwd<<<dim3(1024), 256, 0, stream>>>(Qw, Kw, VT, MP, (float*)d_out);
}

// Round 7
// 229.357 us; speedup vs baseline: 1.2141x; 1.2141x over previous
//
#include <hip/hip_runtime.h>
#include <hip/hip_bf16.h>
#include <math.h>

typedef float  f32x4  __attribute__((ext_vector_type(4)));
typedef float  f32x16 __attribute__((ext_vector_type(16)));
typedef short  s16x8  __attribute__((ext_vector_type(8)));
typedef __bf16 bf16x8 __attribute__((ext_vector_type(8)));
typedef unsigned int u32;
typedef unsigned int u32x4 __attribute__((ext_vector_type(4)));
typedef unsigned short u16;
typedef unsigned long long u64;

#define DEVI static __device__ __forceinline__

#if defined(__has_builtin) && __has_builtin(__builtin_amdgcn_exp2f)
#define EXP2(x) __builtin_amdgcn_exp2f(x)
#else
#define EXP2(x) exp2f(x)
#endif

// one-instruction packed f32->bf16 RNE pair (v_cvt_pk_bf16_f32)
DEVI u32 cvtpk(float lo, float hi) {
  u32 r;
  asm("v_cvt_pk_bf16_f32 %0, %1, %2" : "=v"(r) : "v"(lo), "v"(hi));
  return r;
}

DEVI f32x4 mfma_bf16(s16x8 a, s16x8 b, f32x4 c) {
  return __builtin_amdgcn_mfma_f32_16x16x32_bf16(
      __builtin_bit_cast(bf16x8, a), __builtin_bit_cast(bf16x8, b), c, 0, 0, 0);
}

DEVI f32x16 mfma32(s16x8 a, s16x8 b, f32x16 c) {
  return __builtin_amdgcn_mfma_f32_32x32x16_bf16(
      __builtin_bit_cast(bf16x8, a), __builtin_bit_cast(bf16x8, b), c, 0, 0, 0);
}

DEVI void gload_lds16(const void* g, void* l) {
  __builtin_amdgcn_global_load_lds(
      (const __attribute__((address_space(1))) void*)g,
      (__attribute__((address_space(3))) void*)l, 16, 0, 0);
}

// ---------------------------------------------------------------------------
// Kernel 0: bit-pack KEEP bits (parallel: one word per wave, one load/lane).
// int32[8][2048][2048] -> u64[8][32][2048]
// word (b,kt,q): bit l == 1  iff  kv = kt*64+l is KEPT (mask == 0).
// ---------------------------------------------------------------------------
__global__ __launch_bounds__(256)
void mask_pack(const int* __restrict__ mask, u64* __restrict__ mp) {
  const int t = threadIdx.x, lane = t & 63;
  const int gw = blockIdx.x * 4 + (t >> 6);
  const int kt = gw & 31, q = (gw >> 5) & 2047, b = gw >> 16;
  int mv = mask[((size_t)b * 2048 + q) * 2048 + kt * 64 + lane];
  u64 bits = __ballot(mv == 0);
  if (lane == 0) mp[((size_t)b * 32 + kt) * 2048 + q] = bits;
}

// ---------------------------------------------------------------------------
// Kernel 1: QKV projections.  z=0: Q=xq*wq^T+bq (scaled 1/8*log2e, bf16)
//           z=1: K           z=2: V written transposed as VT[b*512+h*64+d][s]
// grid (128, 4, 3), block 256.
// ---------------------------------------------------------------------------
__global__ __launch_bounds__(256, 2)
void qkv_proj(const float* __restrict__ xq, const float* __restrict__ xkv,
              const float* __restrict__ wq, const float* __restrict__ bq,
              const float* __restrict__ wk, const float* __restrict__ bk,
              const float* __restrict__ wv, const float* __restrict__ bv,
              u16* __restrict__ Qo, u16* __restrict__ Ko, u16* __restrict__ VTo)
{
  __shared__ __align__(16) char smem[128 * 272]; // A[0,8K) B[8K,16K); V-transpose
  char* lds_a = smem;
  char* lds_b = smem + 8192;

  const int t = threadIdx.x, lane = t & 63, w = t >> 6;
  const int z = blockIdx.z;
  const float* X  = (z == 0) ? xq : xkv;
  const float* W  = (z == 0) ? wq : (z == 1 ? wk : wv);
  const float* Bv = (z == 0) ? bq : (z == 1 ? bk : bv);

  const int m0 = blockIdx.x * 128, n0 = blockIdx.y * 128;
  const int wr = w >> 1, wc = w & 1, g = lane >> 4, q15 = lane & 15;
  const int srow = t >> 1, shalf = t & 1;

  f32x4 acc[4][4];
  #pragma unroll
  for (int i = 0; i < 4; ++i)
    #pragma unroll
    for (int j = 0; j < 4; ++j) acc[i][j] = (f32x4){0.f, 0.f, 0.f, 0.f};

  const float* gA = X + (size_t)(m0 + srow) * 512 + shalf * 16;
  const float* gB = W + (size_t)(n0 + srow) * 512 + shalf * 16;
  const int wbyte = srow * 64;
  const int sw = (srow & 3) << 4;

  #pragma unroll 1
  for (int kt = 0; kt < 16; ++kt) {
    float4 fa[4], fb[4];
    #pragma unroll
    for (int j = 0; j < 4; ++j) {
      fa[j] = *(const float4*)(gA + kt * 32 + j * 4);
      fb[j] = *(const float4*)(gB + kt * 32 + j * 4);
    }
    __syncthreads();                    // prev compute done before overwrite
    const float* pfa = (const float*)fa;
    const float* pfb = (const float*)fb;
    #pragma unroll
    for (int half = 0; half < 2; ++half) {
      u32x4 wa, wb;
      #pragma unroll
      for (int e2 = 0; e2 < 4; ++e2) {
        wa[e2] = cvtpk(pfa[half * 8 + 2 * e2], pfa[half * 8 + 2 * e2 + 1]);
        wb[e2] = cvtpk(pfb[half * 8 + 2 * e2], pfb[half * 8 + 2 * e2 + 1]);
      }
      *(u32x4*)(lds_a + wbyte + ((shalf * 32 + half * 16) ^ sw)) = wa;
      *(u32x4*)(lds_b + wbyte + ((shalf * 32 + half * 16) ^ sw)) = wb;
    }
    __syncthreads();
    s16x8 afr[4], bfr[4];
    #pragma unroll
    for (int mi = 0; mi < 4; ++mi) {
      int row = wr * 64 + mi * 16 + q15;
      afr[mi] = *(const s16x8*)(lds_a + row * 64 + ((g * 16) ^ ((row & 3) << 4)));
    }
    #pragma unroll
    for (int ni = 0; ni < 4; ++ni) {
      int row = wc * 64 + ni * 16 + q15;
      bfr[ni] = *(const s16x8*)(lds_b + row * 64 + ((g * 16) ^ ((row & 3) << 4)));
    }
    #pragma unroll
    for (int mi = 0; mi < 4; ++mi)
      #pragma unroll
      for (int ni = 0; ni < 4; ++ni)
        acc[mi][ni] = mfma_bf16(afr[mi], bfr[ni], acc[mi][ni]);
  }

  float bias[4];
  #pragma unroll
  for (int ni = 0; ni < 4; ++ni) bias[ni] = Bv[n0 + wc * 64 + ni * 16 + q15];

  if (z < 2) {
    u16* Out = z ? Ko : Qo;
    // Q: fold 1/sqrt(64) * log2(e) so attention works in exp2 domain
    const float scale = z ? 1.0f : 0.18033688011112042f;
    #pragma unroll
    for (int mi = 0; mi < 4; ++mi)
      #pragma unroll
      for (int ni = 0; ni < 4; ++ni)
        #pragma unroll
        for (int r = 0; r < 4; r += 2) {
          int m = m0 + wr * 64 + mi * 16 + g * 4 + r;
          int n = n0 + wc * 64 + ni * 16 + q15;
          u32 pk = cvtpk((acc[mi][ni][r] + bias[ni]) * scale,
                         (acc[mi][ni][r + 1] + bias[ni]) * scale);
          Out[(size_t)m * 512 + n]       = (u16)pk;
          Out[(size_t)(m + 1) * 512 + n] = (u16)(pk >> 16);
        }
  } else {
    __syncthreads();                    // all frag reads done; reuse smem
    #pragma unroll
    for (int mi = 0; mi < 4; ++mi)
      #pragma unroll
      for (int ni = 0; ni < 4; ++ni)
        #pragma unroll
        for (int r = 0; r < 4; r += 2) {
          int ml = wr * 64 + mi * 16 + g * 4 + r;
          int nl = wc * 64 + ni * 16 + q15;
          *(u32*)(smem + nl * 272 + ml * 2) =
              cvtpk(acc[mi][ni][r] + bias[ni], acc[mi][ni][r + 1] + bias[ni]);
        }
    __syncthreads();
    const int b  = m0 >> 11;
    const int s0 = m0 & 2047;
    #pragma unroll
    for (int nn = 0; nn < 2; ++nn) {
      int n  = nn * 64 + (t >> 2);
      int q4 = t & 3;
      u16* dst = VTo + (size_t)(b * 512 + n0 + n) * 2048 + s0 + q4 * 32;
      #pragma unroll
      for (int jj = 0; jj < 4; ++jj)
        *(s16x8*)(dst + jj * 8) = *(const s16x8*)(smem + n * 272 + q4 * 64 + jj * 16);
    }
  }
}

// ---------------------------------------------------------------------------
// Kernel 2: fused flash attention, 32x32 MFMA form, no-max exp2 softmax.
// Row denominators via ones-column MFMA (o2): P (masked, bf16-packed) feeds
// both PV and the sum -> no VALU lsum, no epilogue shuffles.
// grid.x = h + 8*b + 64*qt; block 256 = 4 waves x 32 q-rows.
// ---------------------------------------------------------------------------
__global__ __launch_bounds__(256, 3)
void attn_fwd(const u16* __restrict__ Q, const u16* __restrict__ K,
              const u16* __restrict__ VT, const u64* __restrict__ MP,
              float* __restrict__ out)
{
  __shared__ __align__(16) char lds_k[2][8192];  // [kv 64][d 64] bf16, swizzled
  __shared__ __align__(16) char lds_v[2][8192];  // [d 64][kv 64] bf16, swizzled

  const int bid = blockIdx.x;
  const int h = bid & 7, b = (bid >> 3) & 7, qt = bid >> 6;
  const int t = threadIdx.x, lane = t & 63, w = t >> 6;
  const int l31 = lane & 31, hi = lane >> 5;
  const int qbase = qt * 128 + w * 32;
  const int swz = (l31 & 7) << 4;

  // Q B-frags (pre-scaled by 0.125*log2e): col=q=l31, k(d) = j*16 + 8*hi + e
  s16x8 qf[4];
  #pragma unroll
  for (int j = 0; j < 4; ++j)
    qf[j] = *(const s16x8*)(Q + (size_t)(b * 2048 + qbase + l31) * 512
                              + h * 64 + j * 16 + hi * 8);
  asm volatile("" ::: "memory");        // pin qf loads before STAGE(0)

  f32x16 o0 = {0.f,0.f,0.f,0.f,0.f,0.f,0.f,0.f,0.f,0.f,0.f,0.f,0.f,0.f,0.f,0.f};
  f32x16 o1 = o0, o2 = o0;
  const f32x16 ZZ = o0;
  const s16x8 onesf = {0x3F80,0x3F80,0x3F80,0x3F80,0x3F80,0x3F80,0x3F80,0x3F80};

  const int srow8 = lane >> 3, slot = lane & 7;
  const int rl0 = w * 16 + srow8, rl1 = rl0 + 8;

  // loop-carried staging pointers (advance by consts; no per-iter recompute)
  const u16* kP0 = K + (size_t)(b * 2048 + rl0) * 512 + h * 64 + (slot ^ (rl0 & 7)) * 8;
  const u16* kP1 = K + (size_t)(b * 2048 + rl1) * 512 + h * 64 + (slot ^ (rl1 & 7)) * 8;
  const u16* vP0 = VT + (size_t)(b * 512 + h * 64 + rl0) * 2048 + (slot ^ (rl0 & 7)) * 8;
  const u16* vP1 = VT + (size_t)(b * 512 + h * 64 + rl1) * 2048 + (slot ^ (rl1 & 7)) * 8;
  const u64* mpP = MP + (size_t)b * 32 * 2048 + qbase + l31;

  // prologue: stage tile 0 into buf 0, prefetch mask word 0
  gload_lds16(kP0, &lds_k[0][w * 2048]);
  gload_lds16(vP0, &lds_v[0][w * 2048]);
  gload_lds16(kP1, &lds_k[0][w * 2048 + 1024]);
  gload_lds16(vP1, &lds_v[0][w * 2048 + 1024]);
  asm volatile("" ::: "memory");        // stage(0) issued before mask prefetch
  u64 pm = *mpP;

  #pragma unroll 1
  for (int kt = 0; kt < 32; ++kt) {
    const int cur = kt & 1;
    const u64 kw = pm;
    if (kt + 1 < 32) {
      kP0 += 32768; kP1 += 32768; vP0 += 64; vP1 += 64; mpP += 2048;
      gload_lds16(kP0, &lds_k[cur ^ 1][w * 2048]);
      gload_lds16(vP0, &lds_v[cur ^ 1][w * 2048]);
      gload_lds16(kP1, &lds_k[cur ^ 1][w * 2048 + 1024]);
      gload_lds16(vP1, &lds_v[cur ^ 1][w * 2048 + 1024]);
      asm volatile("" ::: "memory");
      pm = *mpP;
      // newer than {stage(kt), mask(kt)}: stage(kt+1)=4 + mask(kt+1)=1 = 5
      asm volatile("s_waitcnt vmcnt(5)" ::: "memory");
    } else {
      asm volatile("s_waitcnt vmcnt(0)" ::: "memory");
    }
    asm volatile("s_barrier" ::: "memory");

    // ---- S^T = K * Q^T over d=64 (4 mfma per kv-32 tile) ----
    f32x16 p0, p1;
    {
      s16x8 a0 = *(const s16x8*)(&lds_k[cur][ l31       * 128 + ((0 * 32 + hi * 16) ^ swz)]);
      s16x8 a1 = *(const s16x8*)(&lds_k[cur][(l31 + 32) * 128 + ((0 * 32 + hi * 16) ^ swz)]);
      p0 = mfma32(a0, qf[0], ZZ);
      p1 = mfma32(a1, qf[0], ZZ);
    }
    #pragma unroll
    for (int j = 1; j < 4; ++j) {
      s16x8 a0 = *(const s16x8*)(&lds_k[cur][ l31       * 128 + ((j * 32 + hi * 16) ^ swz)]);
      s16x8 a1 = *(const s16x8*)(&lds_k[cur][(l31 + 32) * 128 + ((j * 32 + hi * 16) ^ swz)]);
      p0 = mfma32(a0, qf[j], p0);
      p1 = mfma32(a1, qf[j], p1);
    }

    // ---- masked exp2 -> packed bf16 words (raw v_exp_f32, v_cvt_pk) ----
    // own kv of word (t2,q): 32*t2 + 8*(q>>1) + 2*(q&1) + 4*hi (+0/+1)
    u64 kws = kw >> (hi * 4);
    u32 mm0 = (u32)kws, mm1 = (u32)(kws >> 32);
    u32 wds[16];
    #pragma unroll
    for (int t2 = 0; t2 < 2; ++t2) {
      const u32 mmw = t2 ? mm1 : mm0;
      #pragma unroll
      for (int q = 0; q < 8; ++q) {
        const int bp = 8 * (q >> 1) + 2 * (q & 1);
        float s0v = t2 ? p1[2 * q] : p0[2 * q];
        float s1v = t2 ? p1[2 * q + 1] : p0[2 * q + 1];
        float e0 = EXP2(s0v), e1 = EXP2(s1v);
        u32 k0 = (u32)((int)(mmw << (31 - bp)) >> 31);        // sext bit bp
        u32 k1 = (u32)((int)(mmw << (30 - bp)) >> 31);        // sext bit bp+1
        e0 = __builtin_bit_cast(float, __builtin_bit_cast(u32, e0) & k0);
        e1 = __builtin_bit_cast(float, __builtin_bit_cast(u32, e1) & k1);
        wds[t2 * 8 + q] = cvtpk(e0, e1);
      }
    }

    // ---- PV + ones-column row sums: per j exchange 2 word-pairs (lane^32),
    //      then 3 mfma (o0, o1, o2-sum) ----
    #pragma unroll
    for (int j = 0; j < 4; ++j) {
      const int ia = 2 * j, ib = 2 * j + 1;
      u32 wa0 = wds[(ia >> 2) * 8 + 2 * (ia & 3)];
      u32 wa1 = wds[(ia >> 2) * 8 + 2 * (ia & 3) + 1];
      u32 wb0 = wds[(ib >> 2) * 8 + 2 * (ib & 3)];
      u32 wb1 = wds[(ib >> 2) * 8 + 2 * (ib & 3) + 1];
      asm("v_permlane32_swap_b32 %0, %1" : "+v"(wa0), "+v"(wb0));
      asm("v_permlane32_swap_b32 %0, %1" : "+v"(wa1), "+v"(wb1));
      u32x4 aw = {wa0, wa1, wb0, wb1};
      s16x8 af = __builtin_bit_cast(s16x8, aw);
      s16x8 v0 = *(const s16x8*)(&lds_v[cur][ l31       * 128 + ((j * 32 + hi * 16) ^ swz)]);
      s16x8 v1 = *(const s16x8*)(&lds_v[cur][(l31 + 32) * 128 + ((j * 32 + hi * 16) ^ swz)]);
      o0 = mfma32(af, v0, o0);
      o1 = mfma32(af, v1, o1);
      o2 = mfma32(af, onesf, o2);
    }

    asm volatile("s_waitcnt lgkmcnt(0)" ::: "memory");
    __builtin_amdgcn_sched_barrier(0);
    asm volatile("s_barrier" ::: "memory");   // reads done before next overwrite
  }

  // ---- epilogue: o2[reg] IS the row denominator for o0/o1[reg] ----
  #pragma unroll
  for (int reg = 0; reg < 16; ++reg) {
    const int ql = (reg & 3) + 8 * (reg >> 2) + 4 * hi;
    const float linv = 1.0f / o2[reg];
    float* po = out + (size_t)(b * 2048 + qbase + ql) * 512 + h * 64 + l31;
    po[0]  = o0[reg] * linv;
    po[32] = o1[reg] * linv;
  }
}

extern "C" void kernel_launch(void* const* d_in, const int* in_sizes, int n_in,
                              void* d_out, int out_size, void* d_ws, size_t ws_size,
                              hipStream_t stream) {
  const float* xq  = (const float*)d_in[0];
  const float* xkv = (const float*)d_in[1];
  const int*   msk = (const int*)d_in[2];
  const float* wq  = (const float*)d_in[3];
  const float* bq  = (const float*)d_in[4];
  const float* wk  = (const float*)d_in[5];
  const float* bk  = (const float*)d_in[6];
  const float* wv  = (const float*)d_in[7];
  const float* bv  = (const float*)d_in[8];

  u16* Qw = (u16*)d_ws;                          // [16384][512] bf16 (x 0.1803)
  u16* Kw = Qw + (size_t)16384 * 512;            // [16384][512] bf16
  u16* VT = Kw + (size_t)16384 * 512;            // [4096][2048] bf16 (V^T)
  u64* MP = (u64*)(VT + (size_t)4096 * 2048);    // [8][32][2048] packed keep bits

  mask_pack<<<dim3(131072), 256, 0, stream>>>(msk, MP);
  qkv_proj<<<dim3(128, 4, 3), 256, 0, stream>>>(xq, xkv, wq, bq, wk, bk, wv, bv,
                                                Qw, Kw, VT);
  attn_fwd<<<dim3(1024), 256, 0, stream>>>(Qw, Kw, VT, MP, (float*)d_out);
}